// Round 1
// baseline (11321.059 us; speedup 1.0000x reference)
//
#include <hip/hip_runtime.h>
#include <hip/hip_bf16.h>
#include <math.h>

#define B 16
#define S 32
#define W 32
#define T 64
#define H2 512
#define Hf 256
#define F 128
#define A 128
#define V 32000
#define SW 1024
#define NSTEP 63
#define VP1 32001
#define NSLAB 501   // 501*64 = 32064 >= 32001 vocab columns

__device__ __forceinline__ float frcp(float x){ return __builtin_amdgcn_rcpf(x); }
__device__ __forceinline__ float fexp_(float x){ return __expf(x); }
__device__ __forceinline__ float fsigm(float x){ return frcp(1.f + __expf(-x)); }
__device__ __forceinline__ float ftanh_(float x){
    float e = __expf(-2.f*fabsf(x));
    float t = (1.f - e)*frcp(1.f + e);
    return x >= 0.f ? t : -t;
}

// ---------------- init ----------------
__global__ __launch_bounds__(256) void k_init(const float* __restrict__ state,
                       float* __restrict__ h0, float* __restrict__ c_g,
                       float* __restrict__ ctx_g, float* __restrict__ cov,
                       float* __restrict__ loss) {
    int idx = blockIdx.x*256 + threadIdx.x;   // grid 64 blocks -> 16384 threads
    cov[idx] = 0.f;
    if (idx < B) loss[idx] = 0.f;
    if (idx < B*H2) {
        int b = idx >> 9, j = idx & 511;
        h0[idx]    = state[b*2*H2 + j];
        c_g[idx]   = state[b*2*H2 + H2 + j];
        ctx_g[idx] = 0.f;
    }
}

// ---------------- precompute ws_aT[b][a][n] = ws[b,n,:]@Wa_word[:,a] + b_a[a] ----------------
__global__ __launch_bounds__(256) void k_wsa(
    const float* __restrict__ ws, const float* __restrict__ W_a, const float* __restrict__ b_a,
    float* __restrict__ ws_aT)
{
    __shared__ float wss2[512][20];  // [k][n_local], pad 20 for banks + float4 alignment
    int b = blockIdx.x, nt = blockIdx.y, tid = threadIdx.x;
    int n0 = nt*16;
    const float* wsrc = ws + ((size_t)(b*SW + n0))*H2;
    for (int i = tid; i < 16*512; i += 256) {
        int n_l = i >> 9, k = i & 511;
        wss2[k][n_l] = wsrc[i];
    }
    __syncthreads();
    int a = tid & 127, nh = tid >> 7;  // nh in {0,1}: n-halves of 8
    float acc[8];
    float ba = b_a[a];
    #pragma unroll
    for (int j = 0; j < 8; ++j) acc[j] = ba;
    for (int k = 0; k < H2; ++k) {
        float wa = W_a[k*A + a];
        const float4 u0 = *(const float4*)&wss2[k][nh*8];
        const float4 u1 = *(const float4*)&wss2[k][nh*8 + 4];
        acc[0] += u0.x*wa; acc[1] += u0.y*wa; acc[2] += u0.z*wa; acc[3] += u0.w*wa;
        acc[4] += u1.x*wa; acc[5] += u1.y*wa; acc[6] += u1.z*wa; acc[7] += u1.w*wa;
    }
    float* dst = ws_aT + ((size_t)(b*A + a))*SW + n0 + nh*8;
    #pragma unroll
    for (int j = 0; j < 8; ++j) dst[j] = acc[j];
}

// ---------------- LSTM gates + cell (grid: B x 8, 256 thr) ----------------
__global__ __launch_bounds__(256) void k_gates(
    const float* __restrict__ emb, const float* __restrict__ W_cc, const float* __restrict__ b_cc,
    const float* __restrict__ Wx, const float* __restrict__ Wh, const float* __restrict__ b_lstm,
    const int* __restrict__ summary, const int* __restrict__ sumlen,
    const float* __restrict__ ctx_g, const float* __restrict__ h_in,
    float* __restrict__ h_out, float* __restrict__ c_g, float* __restrict__ out_g, int t)
{
    __shared__ float ec[640];   // [0:128) emb row, [128:640) ctx
    __shared__ float xh[640];   // [0:128) x result, [128:640) h
    __shared__ float red[256];
    int b = blockIdx.x, q = blockIdx.y, tid = threadIdx.x;
    int tok = summary[b*T + t];
    for (int i = tid; i < 640; i += 256) {
        ec[i] = (i < F) ? emb[tok*F + i] : ctx_g[b*H2 + i - F];
        xh[i] = (i < F) ? 0.f : h_in[b*H2 + i - F];
    }
    __syncthreads();
    // x = [emb, ctx] @ W_cc + b_cc : 128 outputs, 2 threads each (k halves of 320)
    {
        int f = tid & 127, half = tid >> 7;
        float xa = 0.f;
        int kk0 = half*320, kk1 = kk0 + 320;
        for (int k = kk0; k < kk1; ++k) xa += ec[k]*W_cc[k*F + f];
        red[tid] = xa;
    }
    __syncthreads();
    if (tid < F) xh[tid] = red[tid] + red[tid + 128] + b_cc[tid];
    __syncthreads();
    // gates for cols col = q*64 + j ; k split into quarters of 160
    int j = tid & 63, kq = tid >> 6;
    int col = q*64 + j;
    float g0 = 0.f, g1 = 0.f, g2 = 0.f, g3 = 0.f;
    int k0 = kq*160, k1 = k0 + 160;
    for (int k = k0; k < k1; ++k) {
        float xv = xh[k];
        const float* wr = (k < F) ? (Wx + (size_t)k*(4*H2) + col)
                                  : (Wh + (size_t)(k - F)*(4*H2) + col);
        g0 += xv*wr[0]; g1 += xv*wr[H2]; g2 += xv*wr[2*H2]; g3 += xv*wr[3*H2];
    }
    float gv0 = 0.f, gv1 = 0.f, gv2 = 0.f, gv3 = 0.f;
    red[tid] = g0; __syncthreads();
    if (tid < 64) gv0 = red[tid] + red[tid+64] + red[tid+128] + red[tid+192];
    __syncthreads();
    red[tid] = g1; __syncthreads();
    if (tid < 64) gv1 = red[tid] + red[tid+64] + red[tid+128] + red[tid+192];
    __syncthreads();
    red[tid] = g2; __syncthreads();
    if (tid < 64) gv2 = red[tid] + red[tid+64] + red[tid+128] + red[tid+192];
    __syncthreads();
    red[tid] = g3; __syncthreads();
    if (tid < 64) gv3 = red[tid] + red[tid+64] + red[tid+128] + red[tid+192];
    if (tid < 64) {
        int hh = q*64 + tid;
        float gi = gv0 + b_lstm[hh];
        float gf = gv1 + b_lstm[H2 + hh];
        float gg = gv2 + b_lstm[2*H2 + hh];
        float go = gv3 + b_lstm[3*H2 + hh];
        float cold = c_g[b*H2 + hh];
        float cn = fsigm(gf)*cold + fsigm(gi)*ftanh_(gg);
        float o  = fsigm(go)*ftanh_(cn);
        float valid = (sumlen[b] - t - 1 > 0) ? 1.f : 0.f;
        out_g[b*H2 + hh] = o;
        c_g[b*H2 + hh]   = cn*valid;
        h_out[b*H2 + hh] = o*valid;
    }
}

// ---------------- attention scores (grid: B x 8 slabs of 128 n, 128 thr) ----------------
__global__ __launch_bounds__(128) void k_score(
    const float* __restrict__ ws_aT, const float* __restrict__ out_g,
    const float* __restrict__ cov, const float* __restrict__ W_a,
    const float* __restrict__ v_a, const int* __restrict__ text_length,
    float* __restrict__ scores)
{
    __shared__ float outs[H2];
    __shared__ float wos[A], was[A], vas[A];
    int b = blockIdx.x, slab = blockIdx.y, tid = threadIdx.x;
    for (int i = tid; i < H2; i += 128) outs[i] = out_g[b*H2 + i];
    was[tid] = W_a[2*H2*A + tid];   // wa_cov
    vas[tid] = v_a[tid];
    __syncthreads();
    // wo[a] = out @ Wa_out (redundant per slab-block; keeps it fused)
    float woa = 0.f;
    for (int k = 0; k < H2; ++k) woa += outs[k]*W_a[(H2 + k)*A + tid];
    wos[tid] = woa;
    __syncthreads();
    int n = slab*128 + tid;
    float cv = cov[b*SW + n];
    float acc = 0.f;
    const float* wp = ws_aT + (size_t)b*A*SW + n;
    for (int a = 0; a < A; ++a)
        acc += ftanh_(wp[(size_t)a*SW] + wos[a] + cv*was[a]) * vas[a];
    int sent = n >> 5, w = n & 31;
    scores[b*SW + n] = (w < text_length[b*S + sent]) ? acc : -1e9f;
}

// ---------------- softmax + weighted sum partials + coverage (grid: B x 32, 256 thr) ----------------
__global__ __launch_bounds__(256) void k_ctx4(
    const float* __restrict__ scores, const float* __restrict__ ws,
    const float* __restrict__ ss, float* __restrict__ part,
    float* __restrict__ cov, float* __restrict__ covloss_t,
    const int* __restrict__ sumlen, int t)
{
    __shared__ float red[256];
    __shared__ float attn_s[32];
    int b = blockIdx.x, slab = blockIdx.y, tid = threadIdx.x;
    float s0 = scores[b*SW + tid], s1 = scores[b*SW + 256 + tid];
    float s2 = scores[b*SW + 512 + tid], s3 = scores[b*SW + 768 + tid];
    red[tid] = fmaxf(fmaxf(s0, s1), fmaxf(s2, s3));
    __syncthreads();
    for (int off = 128; off > 0; off >>= 1) { if (tid < off) red[tid] = fmaxf(red[tid], red[tid+off]); __syncthreads(); }
    float M = red[0];
    __syncthreads();
    red[tid] = fexp_(s0 - M) + fexp_(s1 - M) + fexp_(s2 - M) + fexp_(s3 - M);
    __syncthreads();
    for (int off = 128; off > 0; off >>= 1) { if (tid < off) red[tid] += red[tid+off]; __syncthreads(); }
    float invS = frcp(red[0]);
    if (tid < 32) attn_s[tid] = fexp_(scores[b*SW + slab*32 + tid] - M) * invS;
    __syncthreads();
    // partial ctx4: this slab is exactly sentence `slab`
    int n0 = slab*32;
    float acc0 = 0.f, acc1 = 0.f, asum = 0.f;
    for (int nn = 0; nn < 32; ++nn) {
        float a = attn_s[nn];
        asum += a;
        const float* wrow = ws + ((size_t)(b*SW + n0 + nn))*H2;
        acc0 += a * wrow[tid];
        acc1 += a * wrow[tid + 256];
    }
    float ssv0 = ss[((size_t)(b*S + slab))*H2 + tid]       * asum;
    float ssv1 = ss[((size_t)(b*S + slab))*H2 + tid + 256] * asum;
    float* pp = part + ((size_t)(b*32 + slab))*1024;
    pp[tid] = acc0; pp[tid+256] = acc1; pp[tid+512] = ssv0; pp[tid+768] = ssv1;
    // slab 0: covloss + coverage update (uses old coverage)
    if (slab == 0) {
        float valid = (sumlen[b] - t - 1 > 0) ? 1.f : 0.f;
        float cl = 0.f;
        for (int i = tid; i < SW; i += 256) {
            float at = fexp_(scores[b*SW + i] - M) * invS;
            float cv = cov[b*SW + i];
            cl += fminf(cv, at);
            cov[b*SW + i] = cv + at*valid;
        }
        __syncthreads();
        red[tid] = cl; __syncthreads();
        for (int off = 128; off > 0; off >>= 1) { if (tid < off) red[tid] += red[tid+off]; __syncthreads(); }
        if (tid == 0) covloss_t[b] = red[0];
    }
}

// ---------------- ctx_new = ctx4 @ W_rc + b_rc (grid: B x 4, 128 thr) ----------------
__global__ __launch_bounds__(128) void k_ctxnew(
    const float* __restrict__ part, const float* __restrict__ W_rc, const float* __restrict__ b_rc,
    const int* __restrict__ sumlen, float* __restrict__ ctxn_raw, float* __restrict__ ctx_g, int t)
{
    __shared__ float c4s[1024];
    int b = blockIdx.x, hq = blockIdx.y, tid = threadIdx.x;
    const float* pp = part + (size_t)b*32*1024;
    for (int d = tid; d < 1024; d += 128) {
        float a = 0.f;
        for (int s = 0; s < 32; ++s) a += pp[s*1024 + d];
        c4s[d] = a;
    }
    __syncthreads();
    int h = hq*128 + tid;
    float acc = b_rc[h];
    for (int d = 0; d < 1024; ++d) acc += c4s[d]*W_rc[(size_t)d*H2 + h];
    ctxn_raw[b*H2 + h] = acc;
    float valid = (sumlen[b] - t - 1 > 0) ? 1.f : 0.f;
    ctx_g[b*H2 + h] = acc*valid;
}

// ---------------- hid = relu([ctx_new, out] @ W1 + b1) (grid: B x 2, 128 thr) ----------------
__global__ __launch_bounds__(128) void k_hid(
    const float* __restrict__ ctxn_raw, const float* __restrict__ out_g,
    const float* __restrict__ W1, const float* __restrict__ b1, float* __restrict__ hid)
{
    __shared__ float cs[H2], os[H2];
    int b = blockIdx.x, jq = blockIdx.y, tid = threadIdx.x;
    for (int i = tid; i < H2; i += 128) { cs[i] = ctxn_raw[b*H2 + i]; os[i] = out_g[b*H2 + i]; }
    __syncthreads();
    int jcol = jq*128 + tid;
    float a = b1[jcol];
    for (int d = 0; d < H2; ++d) a += cs[d]*W1[(size_t)d*Hf + jcol];
    for (int d = 0; d < H2; ++d) a += os[d]*W1[(size_t)(H2 + d)*Hf + jcol];
    hid[b*Hf + jcol] = fmaxf(a, 0.f);
}

// ---------------- vocab logits: per-slab (max, sumexp) (grid: NSLAB, 256 thr) ----------------
__global__ __launch_bounds__(256) void k_logits(
    const float* __restrict__ hid, const float* __restrict__ W2, const float* __restrict__ b2,
    float* __restrict__ m_slab, float* __restrict__ s_slab)
{
    __shared__ float hs2[Hf][B];     // transposed: float4 per r
    __shared__ float red[B][64];
    __shared__ float mc[B];
    int blk = blockIdx.x, tid = threadIdx.x;
    int c = tid & 63, bq = tid >> 6;     // 4 b-groups of 4
    int v = blk*64 + c;
    for (int i = tid; i < B*Hf; i += 256) { int bb = i >> 8, r = i & 255; hs2[r][bb] = hid[i]; }
    __syncthreads();
    bool ok = v < VP1;
    float acc[4] = {0.f, 0.f, 0.f, 0.f};
    if (ok) {
        for (int r = 0; r < Hf; ++r) {
            float w = W2[(size_t)r*VP1 + v];
            const float4 h4 = *(const float4*)&hs2[r][bq*4];
            acc[0] += h4.x*w; acc[1] += h4.y*w; acc[2] += h4.z*w; acc[3] += h4.w*w;
        }
        float bb = b2[v];
        #pragma unroll
        for (int jj = 0; jj < 4; ++jj) acc[jj] += bb;
    }
    #pragma unroll
    for (int jj = 0; jj < 4; ++jj) red[bq*4 + jj][c] = ok ? acc[jj] : -1e30f;
    __syncthreads();
    if (tid < B) {
        float m = -1e30f;
        for (int i = 0; i < 64; ++i) m = fmaxf(m, red[tid][i]);
        m_slab[tid*NSLAB + blk] = m;
        mc[tid] = m;
    }
    __syncthreads();
    #pragma unroll
    for (int jj = 0; jj < 4; ++jj) red[bq*4 + jj][c] = ok ? fexp_(acc[jj] - mc[bq*4 + jj]) : 0.f;
    __syncthreads();
    if (tid < B) {
        float s = 0.f;
        for (int i = 0; i < 64; ++i) s += red[tid][i];
        s_slab[tid*NSLAB + blk] = s;
    }
}

// ---------------- combine slabs, target logit, loss accumulate (1 block, 256 thr) ----------------
__global__ __launch_bounds__(256) void k_final(
    const float* __restrict__ m_slab, const float* __restrict__ s_slab,
    const float* __restrict__ hid, const float* __restrict__ W2, const float* __restrict__ b2,
    const int* __restrict__ summary, const int* __restrict__ sumlen,
    const float* __restrict__ covloss_t, float* __restrict__ loss,
    float* __restrict__ d_out, int t)
{
    int tid = threadIdx.x;
    int b = tid >> 4, g = tid & 15;
    float m = -1e30f;
    for (int sIdx = g; sIdx < NSLAB; sIdx += 16) m = fmaxf(m, m_slab[b*NSLAB + sIdx]);
    for (int off = 8; off > 0; off >>= 1) m = fmaxf(m, __shfl_down(m, off, 16));
    m = __shfl(m, 0, 16);
    float s = 0.f;
    for (int sIdx = g; sIdx < NSLAB; sIdx += 16) s += s_slab[b*NSLAB + sIdx]*fexp_(m_slab[b*NSLAB + sIdx] - m);
    for (int off = 8; off > 0; off >>= 1) s += __shfl_down(s, off, 16);
    int tok = summary[b*T + t + 1];
    int tgt = (tok == -1) ? V : tok;
    float d = 0.f;
    for (int r = g; r < Hf; r += 16) d += hid[b*Hf + r]*W2[(size_t)r*VP1 + tgt];
    for (int off = 8; off > 0; off >>= 1) d += __shfl_down(d, off, 16);
    if (g == 0) {
        float logit = d + b2[tgt];
        float logp = logit - m - __logf(s);
        float valid = (sumlen[b] - t - 1 > 0) ? 1.f : 0.f;
        float L = loss[b] + valid*(-logp + covloss_t[b]);
        loss[b] = L;
        if (t == NSTEP - 1) d_out[b] = L / ((float)sumlen[b] - 1.f);
    }
}

extern "C" void kernel_launch(void* const* d_in, const int* in_sizes, int n_in,
                              void* d_out, int out_size, void* d_ws, size_t ws_size,
                              hipStream_t stream) {
    const float* text_states = (const float*)d_in[0];
    const float* sent_states = (const float*)d_in[1];
    const int*   text_length = (const int*)d_in[2];
    const float* state       = (const float*)d_in[3];
    const int*   summary     = (const int*)d_in[4];
    const int*   sumlen      = (const int*)d_in[5];
    const float* emb    = (const float*)d_in[6];
    const float* W_cc   = (const float*)d_in[7];
    const float* b_cc   = (const float*)d_in[8];
    const float* Wx     = (const float*)d_in[9];
    const float* Wh     = (const float*)d_in[10];
    const float* b_lstm = (const float*)d_in[11];
    const float* W_a    = (const float*)d_in[12];
    const float* b_a    = (const float*)d_in[13];
    const float* v_a    = (const float*)d_in[14];
    const float* W_rc   = (const float*)d_in[15];
    const float* b_rc   = (const float*)d_in[16];
    const float* W1     = (const float*)d_in[17];
    const float* b1     = (const float*)d_in[18];
    const float* W2     = (const float*)d_in[19];
    const float* b2     = (const float*)d_in[20];
    float* out = (float*)d_out;

    float* p = (float*)d_ws;
    float* ws_aT     = p; p += (size_t)B*A*SW;    // 2,097,152
    float* h0        = p; p += B*H2;
    float* h1        = p; p += B*H2;
    float* c_g       = p; p += B*H2;
    float* out_g     = p; p += B*H2;
    float* ctx_g     = p; p += B*H2;
    float* ctxn_raw  = p; p += B*H2;
    float* cov       = p; p += B*SW;
    float* scores    = p; p += B*SW;
    float* part      = p; p += (size_t)B*32*1024; // 524,288
    float* hid       = p; p += B*Hf;
    float* m_slab    = p; p += B*NSLAB;
    float* s_slab    = p; p += B*NSLAB;
    float* covloss_t = p; p += B;
    float* loss      = p; p += B;

    k_init<<<64, 256, 0, stream>>>(state, h0, c_g, ctx_g, cov, loss);
    k_wsa<<<dim3(B, 64), 256, 0, stream>>>(text_states, W_a, b_a, ws_aT);
    for (int t = 0; t < NSTEP; ++t) {
        float* hin  = (t & 1) ? h1 : h0;
        float* hout = (t & 1) ? h0 : h1;
        k_gates<<<dim3(B, 8), 256, 0, stream>>>(emb, W_cc, b_cc, Wx, Wh, b_lstm, summary, sumlen,
                                                ctx_g, hin, hout, c_g, out_g, t);
        k_score<<<dim3(B, 8), 128, 0, stream>>>(ws_aT, out_g, cov, W_a, v_a, text_length, scores);
        k_ctx4<<<dim3(B, 32), 256, 0, stream>>>(scores, text_states, sent_states, part, cov, covloss_t, sumlen, t);
        k_ctxnew<<<dim3(B, 4), 128, 0, stream>>>(part, W_rc, b_rc, sumlen, ctxn_raw, ctx_g, t);
        k_hid<<<dim3(B, 2), 128, 0, stream>>>(ctxn_raw, out_g, W1, b1, hid);
        k_logits<<<NSLAB, 256, 0, stream>>>(hid, W2, b2, m_slab, s_slab);
        k_final<<<1, 256, 0, stream>>>(m_slab, s_slab, hid, W2, b2, summary, sumlen, covloss_t, loss, out, t);
    }
}